// Round 1
// baseline (1602.228 us; speedup 1.0000x reference)
//
#include <hip/hip_runtime.h>
#include <hip/hip_bf16.h>

typedef __hip_bfloat16 bf16;

#define NB 128   // B*TO
#define CC 64    // channels
#define TT 1024  // time

// ---------------------------------------------------------------------------
// Kernel 1: q/k/v = W{q,k,v} @ x  for one (n, 64-wide t tile) per block.
// x staged in LDS as bf16 (accuracy fine: downstream q/k/v stored bf16 anyway),
// all three weight matrices staged in LDS fp32 (48 KB). Output bf16 -> ws.
// ---------------------------------------------------------------------------
__global__ __launch_bounds__(256) void qkv_proj(
    const float* __restrict__ x,
    const float* __restrict__ Wq, const float* __restrict__ Wk,
    const float* __restrict__ Wv,
    bf16* __restrict__ q, bf16* __restrict__ k, bf16* __restrict__ v)
{
  __shared__ bf16  xs[64][66];          // [c][t] ; 66 stride: 2-way max (free)
  __shared__ float wqs[4096], wks[4096], wvs[4096];  // [o*64+c]

  const int n  = blockIdx.y;
  const int t0 = blockIdx.x * 64;
  const int tid = threadIdx.x;
  const size_t nbase = (size_t)n * CC * TT;

  for (int i = tid; i < 4096; i += 256) {
    int c = i >> 6, t = i & 63;
    xs[c][t] = __float2bfloat16(x[nbase + (size_t)c * TT + t0 + t]);
    wqs[i] = Wq[i]; wks[i] = Wk[i]; wvs[i] = Wv[i];
  }
  __syncthreads();

  const int t  = tid & 63;   // lanes vary t -> coalesced/conflict-free
  const int og = tid >> 6;   // wave-uniform output-channel group

  for (int j = 0; j < 16; j++) {
    const int o = og * 16 + j;
    float aq = 0.f, ak = 0.f, av = 0.f;
    #pragma unroll
    for (int c4 = 0; c4 < 16; c4++) {
      float4 wq4 = *(const float4*)&wqs[o * 64 + c4 * 4];  // broadcast
      float4 wk4 = *(const float4*)&wks[o * 64 + c4 * 4];
      float4 wv4 = *(const float4*)&wvs[o * 64 + c4 * 4];
      float x0 = __bfloat162float(xs[c4 * 4 + 0][t]);
      float x1 = __bfloat162float(xs[c4 * 4 + 1][t]);
      float x2 = __bfloat162float(xs[c4 * 4 + 2][t]);
      float x3 = __bfloat162float(xs[c4 * 4 + 3][t]);
      aq += wq4.x * x0 + wq4.y * x1 + wq4.z * x2 + wq4.w * x3;
      ak += wk4.x * x0 + wk4.y * x1 + wk4.z * x2 + wk4.w * x3;
      av += wv4.x * x0 + wv4.y * x1 + wv4.z * x2 + wv4.w * x3;
    }
    const size_t idx = nbase + (size_t)o * TT + t0 + t;
    q[idx] = __float2bfloat16(aq);
    k[idx] = __float2bfloat16(ak);
    v[idx] = __float2bfloat16(av);
  }
}

// ---------------------------------------------------------------------------
// Kernel 2: flash attention for one (n, 64-query tile) per block.
// Thread layout: lane (tid&63) = query row tq ; wave (tid>>6) = s-group for
// score phase, c-group for PV phase. q row lives in 64 registers.
// K/V tiles staged transposed [s][c] (stride 68 -> aligned float4, odd in
// float4 units -> conflict-free). Online softmax state per row in LDS.
// Writes the attention output (pre-Wo projection) fp32 into d_out.
// ---------------------------------------------------------------------------
__global__ __launch_bounds__(256) void attn(
    const bf16* __restrict__ q, const bf16* __restrict__ k,
    const bf16* __restrict__ v, const float* __restrict__ scale_p,
    float* __restrict__ out)
{
  __shared__ float ks[64][68];   // [s][c]
  __shared__ float vs[64][68];   // [s][c]
  __shared__ float ps[64][65];   // [tq][s]
  __shared__ float mrow[64], lrow[64], arow[64];

  const int n   = blockIdx.y;
  const int qt0 = blockIdx.x * 64;
  const int tid = threadIdx.x;
  const int tq  = tid & 63;      // query row owned by this thread
  const int wv  = tid >> 6;      // wave id
  const size_t nbase = (size_t)n * CC * TT;
  const float scale = *scale_p;

  // q fragment in registers: qr[c] = q[n][c][qt0+tq]
  float qr[64];
  #pragma unroll
  for (int c = 0; c < 64; c++)
    qr[c] = __bfloat162float(q[nbase + (size_t)c * TT + qt0 + tq]);

  float oacc[16];
  #pragma unroll
  for (int j = 0; j < 16; j++) oacc[j] = 0.f;
  if (tid < 64) { mrow[tid] = -1e30f; lrow[tid] = 0.f; }

  for (int st = 0; st < 16; st++) {
    const int s0 = st * 64;
    __syncthreads();  // previous iter's ps/vs consumers done before overwrite
    for (int i = tid; i < 4096; i += 256) {
      int c = i >> 6, ss = i & 63;   // consecutive i -> consecutive ss (coalesced)
      ks[ss][c] = __bfloat162float(k[nbase + (size_t)c * TT + s0 + ss]);
      vs[ss][c] = __bfloat162float(v[nbase + (size_t)c * TT + s0 + ss]);
    }
    __syncthreads();

    // scores: ps[tq][s] for s in wave's 16-column group
    #pragma unroll
    for (int j = 0; j < 16; j++) {
      const int s = wv * 16 + j;
      float acc = 0.f;
      #pragma unroll
      for (int c4 = 0; c4 < 16; c4++) {
        float4 k4 = *(const float4*)&ks[s][c4 * 4];   // wave-broadcast
        acc += qr[c4*4+0]*k4.x + qr[c4*4+1]*k4.y
             + qr[c4*4+2]*k4.z + qr[c4*4+3]*k4.w;
      }
      ps[tq][s] = acc * scale;   // bank = (tq*65+s)%32 -> conflict-free
    }
    __syncthreads();

    // online-softmax row update (one wave; rows across lanes)
    if (tid < 64) {
      const int r = tid;
      float mold = mrow[r];
      float mmax = mold;
      for (int s = 0; s < 64; s++) mmax = fmaxf(mmax, ps[r][s]);
      float a = __expf(mold - mmax);
      float rsum = 0.f;
      for (int s = 0; s < 64; s++) {
        float p = __expf(ps[r][s] - mmax);
        ps[r][s] = p;
        rsum += p;
      }
      mrow[r] = mmax;
      lrow[r] = lrow[r] * a + rsum;
      arow[r] = a;
    }
    __syncthreads();

    // PV accumulate: oacc[j] covers c = wv*16 + j for row tq
    const float a = arow[tq];
    #pragma unroll
    for (int j = 0; j < 16; j++) oacc[j] *= a;
    for (int s = 0; s < 64; s++) {
      const float p = ps[tq][s];          // lanes vary tq -> conflict-free
      #pragma unroll
      for (int j4 = 0; j4 < 4; j4++) {
        float4 v4 = *(const float4*)&vs[s][wv * 16 + j4 * 4]; // broadcast
        oacc[j4*4+0] += p * v4.x;  oacc[j4*4+1] += p * v4.y;
        oacc[j4*4+2] += p * v4.z;  oacc[j4*4+3] += p * v4.w;
      }
    }
  }

  const float linv = 1.f / lrow[tq];
  #pragma unroll
  for (int j = 0; j < 16; j++) {
    const int c = wv * 16 + j;
    out[nbase + (size_t)c * TT + qt0 + tq] = oacc[j] * linv;  // coalesced over tq
  }
}

// ---------------------------------------------------------------------------
// Kernel 3: out = Wo @ attn + x, in place on d_out, one (n, 64-t tile)/block.
// Tile copied to LDS before the barrier; writes only after, so RMW is safe.
// ---------------------------------------------------------------------------
__global__ __launch_bounds__(256) void out_proj(
    const float* __restrict__ x, const float* __restrict__ Wo,
    float* __restrict__ out)
{
  __shared__ float as[64][65];   // [c][t]
  __shared__ float wos[4096];

  const int n  = blockIdx.y;
  const int t0 = blockIdx.x * 64;
  const int tid = threadIdx.x;
  const size_t nbase = (size_t)n * CC * TT;

  for (int i = tid; i < 4096; i += 256) {
    int c = i >> 6, t = i & 63;
    as[c][t] = out[nbase + (size_t)c * TT + t0 + t];
    wos[i] = Wo[i];
  }
  __syncthreads();

  const int t  = tid & 63;
  const int og = tid >> 6;
  for (int j = 0; j < 16; j++) {
    const int o = og * 16 + j;
    float acc = 0.f;
    #pragma unroll
    for (int c4 = 0; c4 < 16; c4++) {
      float4 w4 = *(const float4*)&wos[o * 64 + c4 * 4];
      acc += w4.x * as[c4*4+0][t] + w4.y * as[c4*4+1][t]
           + w4.z * as[c4*4+2][t] + w4.w * as[c4*4+3][t];
    }
    const size_t idx = nbase + (size_t)o * TT + t0 + t;
    out[idx] = acc + x[idx];
  }
}

// ---------------------------------------------------------------------------
extern "C" void kernel_launch(void* const* d_in, const int* in_sizes, int n_in,
                              void* d_out, int out_size, void* d_ws, size_t ws_size,
                              hipStream_t stream) {
  const float* x     = (const float*)d_in[0];
  const float* Wq    = (const float*)d_in[1];
  const float* Wk    = (const float*)d_in[2];
  const float* Wv    = (const float*)d_in[3];
  const float* Wo    = (const float*)d_in[4];
  const float* scale = (const float*)d_in[5];
  float* out = (float*)d_out;

  // workspace: q,k,v as bf16, 16.78 MB each = 50.3 MB total
  const size_t elems = (size_t)NB * CC * TT;
  bf16* qw = (bf16*)d_ws;
  bf16* kw = qw + elems;
  bf16* vw = kw + elems;

  dim3 grid(TT / 64, NB);   // (16, 128)
  dim3 block(256);

  qkv_proj<<<grid, block, 0, stream>>>(x, Wq, Wk, Wv, qw, kw, vw);
  attn<<<grid, block, 0, stream>>>(qw, kw, vw, scale, out);
  out_proj<<<grid, block, 0, stream>>>(x, Wo, out);
}

// Round 2
// 288.048 us; speedup vs baseline: 5.5624x; 5.5624x over previous
//
#include <hip/hip_runtime.h>
#include <hip/hip_bf16.h>

typedef __hip_bfloat16 bf16;
typedef __attribute__((ext_vector_type(8))) short short8;   // 8 bf16 = one MFMA A/B frag
typedef __attribute__((ext_vector_type(4))) float f32x4;    // one MFMA C/D frag

#define NB 128   // B*TO
#define CC 64    // channels
#define TT 1024  // time

__device__ __forceinline__ short f2bfs(float f) {
  bf16 h = __float2bfloat16(f);
  short s; __builtin_memcpy(&s, &h, 2); return s;
}

// ---------------------------------------------------------------------------
// Kernel 1: q/k/v projections. Writes Q,K TRANSPOSED [n][t][c] (bf16) so the
// attn kernel can read MFMA A/B fragments as contiguous-k 16B loads; V stays
// [n][c][s] which is already the PV B-operand layout.
// ---------------------------------------------------------------------------
__global__ __launch_bounds__(256) void qkv_proj(
    const float* __restrict__ x,
    const float* __restrict__ Wq, const float* __restrict__ Wk,
    const float* __restrict__ Wv,
    bf16* __restrict__ qt, bf16* __restrict__ kt, bf16* __restrict__ v)
{
  __shared__ bf16  xs[64][66];
  __shared__ float wqs[4096], wks[4096], wvs[4096];

  const int n  = blockIdx.y;
  const int t0 = blockIdx.x * 64;
  const int tid = threadIdx.x;
  const size_t nbase = (size_t)n * CC * TT;

  for (int i = tid; i < 4096; i += 256) {
    int c = i >> 6, t = i & 63;
    xs[c][t] = __float2bfloat16(x[nbase + (size_t)c * TT + t0 + t]);
    wqs[i] = Wq[i]; wks[i] = Wk[i]; wvs[i] = Wv[i];
  }
  __syncthreads();

  const int t  = tid & 63;
  const int og = tid >> 6;

  short qv[16], kv[16];
  #pragma unroll
  for (int j = 0; j < 16; j++) {
    const int o = og * 16 + j;
    float aq = 0.f, ak = 0.f, av = 0.f;
    #pragma unroll
    for (int c4 = 0; c4 < 16; c4++) {
      float4 wq4 = *(const float4*)&wqs[o * 64 + c4 * 4];
      float4 wk4 = *(const float4*)&wks[o * 64 + c4 * 4];
      float4 wv4 = *(const float4*)&wvs[o * 64 + c4 * 4];
      float x0 = __bfloat162float(xs[c4 * 4 + 0][t]);
      float x1 = __bfloat162float(xs[c4 * 4 + 1][t]);
      float x2 = __bfloat162float(xs[c4 * 4 + 2][t]);
      float x3 = __bfloat162float(xs[c4 * 4 + 3][t]);
      aq += wq4.x * x0 + wq4.y * x1 + wq4.z * x2 + wq4.w * x3;
      ak += wk4.x * x0 + wk4.y * x1 + wk4.z * x2 + wk4.w * x3;
      av += wv4.x * x0 + wv4.y * x1 + wv4.z * x2 + wv4.w * x3;
    }
    qv[j] = f2bfs(aq);
    kv[j] = f2bfs(ak);
    v[nbase + (size_t)o * TT + t0 + t] = __float2bfloat16(av); // coalesced over t
  }
  // q_t/k_t[n][t][c]: 2x16B per thread, rows merged to full lines in L2
  const size_t tbase = nbase + (size_t)(t0 + t) * 64 + og * 16;
  *(short8*)&qt[tbase]     = *(const short8*)&qv[0];
  *(short8*)&qt[tbase + 8] = *(const short8*)&qv[8];
  *(short8*)&kt[tbase]     = *(const short8*)&kv[0];
  *(short8*)&kt[tbase + 8] = *(const short8*)&kv[8];
}

// ---------------------------------------------------------------------------
// Kernel 2: fused MFMA flash attention + output projection + residual.
// Block = (n, 64-query tile), 4 waves. mfma_f32_16x16x32_bf16 throughout.
// A-layout: A[m=lane&15][k=(lane>>4)*8+j]; B[k=(lane>>4)*8+j][n=lane&15];
// C/D: row=(lane>>4)*4+reg, col=lane&15  (m89/m120-verified layouts).
// ---------------------------------------------------------------------------
__global__ __launch_bounds__(256, 4) void attn_fused(
    const bf16* __restrict__ qt, const bf16* __restrict__ kt,
    const bf16* __restrict__ v,  const float* __restrict__ Wo,
    const float* __restrict__ x, const float* __restrict__ scale_p,
    float* __restrict__ out)
{
  __shared__ short ks[64 * 72];    // K tile [s][c], bf16, stride 72 (144B rows)
  __shared__ short vs[64 * 72];    // V tile [c][s], bf16
  __shared__ float Sl[64 * 68];    // S fp32 [t][s] stride 68; P bf16 overlaid
  __shared__ float mrow[64], lrow[64], arow[64];
  __shared__ float pm[256], pl[256];   // [part*64+row] partials

  short* Pl = (short*)Sl;          // P bf16 [t][s], stride 72 (overlay; safe: see barriers)

  const int n   = blockIdx.y;
  const int qt0 = blockIdx.x * 64;
  const int tid = threadIdx.x;
  const int w   = tid >> 6;        // wave id
  const int il  = tid & 15;        // lane&15
  const int q4  = (tid & 63) >> 4; // quad
  const size_t nbase = (size_t)n * CC * TT;
  const float scale = *scale_p;

  // ---- persistent Q A-frags: all 4 m-tiles x 2 k-steps (same for all waves)
  short8 qa[4][2];
  #pragma unroll
  for (int mt = 0; mt < 4; mt++)
    #pragma unroll
    for (int kk = 0; kk < 2; kk++)
      qa[mt][kk] = *(const short8*)&qt[nbase + (size_t)(qt0 + mt * 16 + il) * 64 + kk * 32 + q4 * 8];

  f32x4 oacc[4];
  #pragma unroll
  for (int ct = 0; ct < 4; ct++) oacc[ct] = (f32x4){0.f, 0.f, 0.f, 0.f};

  if (tid < 64) { mrow[tid] = -1e30f; lrow[tid] = 0.f; }

  const int row  = tid & 63;   // softmax: row owned
  const int part = tid >> 6;   // softmax: 16-wide s-segment

  #pragma unroll 1
  for (int st = 0; st < 16; st++) {
    const int s0 = st * 64;
    __syncthreads();   // prior-iter consumers of ks/vs/Pl done

    // ---- stage K,V tiles (coalesced 16B, conflict-free LDS rows)
    #pragma unroll
    for (int p = 0; p < 2; p++) {
      int ci = tid + p * 256;
      int rr = ci >> 3, co = (ci & 7) * 8;
      *(short8*)&ks[rr * 72 + co] = *(const short8*)&kt[nbase + (size_t)(s0 + rr) * 64 + co];
      *(short8*)&vs[rr * 72 + co] = *(const short8*)&v[nbase + (size_t)rr * TT + s0 + co];
    }
    __syncthreads();

    // ---- QK^T: n-split (wave w owns s-cols [w*16, w*16+16))
    short8 bk0 = *(const short8*)&ks[(w * 16 + il) * 72 + q4 * 8];
    short8 bk1 = *(const short8*)&ks[(w * 16 + il) * 72 + 32 + q4 * 8];
    #pragma unroll
    for (int mt = 0; mt < 4; mt++) {
      f32x4 sa = (f32x4){0.f, 0.f, 0.f, 0.f};
      sa = __builtin_amdgcn_mfma_f32_16x16x32_bf16(qa[mt][0], bk0, sa, 0, 0, 0);
      sa = __builtin_amdgcn_mfma_f32_16x16x32_bf16(qa[mt][1], bk1, sa, 0, 0, 0);
      #pragma unroll
      for (int r = 0; r < 4; r++)
        Sl[(mt * 16 + q4 * 4 + r) * 68 + w * 16 + il] = sa[r] * scale;
    }
    __syncthreads();

    // ---- softmax (256 threads: thread = (row, 16-wide part))
    float sv[16];
    #pragma unroll
    for (int jj = 0; jj < 4; jj++) {
      float4 t4 = *(const float4*)&Sl[row * 68 + part * 16 + jj * 4];
      sv[jj*4+0] = t4.x; sv[jj*4+1] = t4.y; sv[jj*4+2] = t4.z; sv[jj*4+3] = t4.w;
    }
    float pmax = sv[0];
    #pragma unroll
    for (int i = 1; i < 16; i++) pmax = fmaxf(pmax, sv[i]);
    pm[part * 64 + row] = pmax;
    const float mold = mrow[row];
    __syncthreads();
    float mnew = fmaxf(fmaxf(pm[row], pm[64 + row]), fmaxf(pm[128 + row], pm[192 + row]));
    mnew = fmaxf(mold, mnew);
    const float alpha = __expf(mold - mnew);
    float psum = 0.f;
    short pu[16];
    #pragma unroll
    for (int i = 0; i < 16; i++) {
      float p = __expf(sv[i] - mnew);
      psum += p;
      pu[i] = f2bfs(p);
    }
    *(short8*)&Pl[row * 72 + part * 16]     = *(const short8*)&pu[0];
    *(short8*)&Pl[row * 72 + part * 16 + 8] = *(const short8*)&pu[8];
    pl[part * 64 + row] = psum;
    if (part == 0) { mrow[row] = mnew; arow[row] = alpha; }
    __syncthreads();
    if (part == 0)
      lrow[row] = lrow[row] * alpha + pl[row] + pl[64 + row] + pl[128 + row] + pl[192 + row];

    // ---- PV: m-split (wave w owns t-rows [w*16, w*16+16))
    float ar[4];
    #pragma unroll
    for (int r = 0; r < 4; r++) ar[r] = arow[w * 16 + q4 * 4 + r];
    #pragma unroll
    for (int ct = 0; ct < 4; ct++)
      #pragma unroll
      for (int r = 0; r < 4; r++) oacc[ct][r] *= ar[r];

    short8 pa0 = *(const short8*)&Pl[(w * 16 + il) * 72 + q4 * 8];
    short8 pa1 = *(const short8*)&Pl[(w * 16 + il) * 72 + 32 + q4 * 8];
    #pragma unroll
    for (int ct = 0; ct < 4; ct++) {
      short8 bv0 = *(const short8*)&vs[(ct * 16 + il) * 72 + q4 * 8];
      short8 bv1 = *(const short8*)&vs[(ct * 16 + il) * 72 + 32 + q4 * 8];
      oacc[ct] = __builtin_amdgcn_mfma_f32_16x16x32_bf16(pa0, bv0, oacc[ct], 0, 0, 0);
      oacc[ct] = __builtin_amdgcn_mfma_f32_16x16x32_bf16(pa1, bv1, oacc[ct], 0, 0, 0);
    }
  }

  // ================= epilogue: normalize, Wo projection, +x, store ==========
  __syncthreads();   // lrow final; all PV reads of Pl done before O overwrites Sl

  float li[4];
  #pragma unroll
  for (int r = 0; r < 4; r++) li[r] = 1.f / lrow[w * 16 + q4 * 4 + r];
  #pragma unroll
  for (int ct = 0; ct < 4; ct++) {
    #pragma unroll
    for (int r = 0; r < 4; r++)
      Sl[(w * 16 + q4 * 4 + r) * 68 + ct * 16 + il] = oacc[ct][r] * li[r];
  }
  __syncthreads();   // O tile [t][c] fp32 complete

  // A-frags of O (own rows only), cvt fp32->bf16
  short8 oa[2];
  #pragma unroll
  for (int kk = 0; kk < 2; kk++) {
    float4 f0 = *(const float4*)&Sl[(w * 16 + il) * 68 + kk * 32 + q4 * 8];
    float4 f1 = *(const float4*)&Sl[(w * 16 + il) * 68 + kk * 32 + q4 * 8 + 4];
    short tmp[8] = { f2bfs(f0.x), f2bfs(f0.y), f2bfs(f0.z), f2bfs(f0.w),
                     f2bfs(f1.x), f2bfs(f1.y), f2bfs(f1.z), f2bfs(f1.w) };
    oa[kk] = *(const short8*)&tmp[0];
  }

  // R[t][o] = sum_c O[t][c] * Wo[o][c]
  f32x4 res[4];
  #pragma unroll
  for (int ot = 0; ot < 4; ot++) res[ot] = (f32x4){0.f, 0.f, 0.f, 0.f};
  #pragma unroll
  for (int ot = 0; ot < 4; ot++) {
    #pragma unroll
    for (int kk = 0; kk < 2; kk++) {
      const float* wp = &Wo[(size_t)(ot * 16 + il) * 64 + kk * 32 + q4 * 8];
      float4 w0 = *(const float4*)&wp[0];
      float4 w1 = *(const float4*)&wp[4];
      short tmp[8] = { f2bfs(w0.x), f2bfs(w0.y), f2bfs(w0.z), f2bfs(w0.w),
                       f2bfs(w1.x), f2bfs(w1.y), f2bfs(w1.z), f2bfs(w1.w) };
      short8 bw = *(const short8*)&tmp[0];
      res[ot] = __builtin_amdgcn_mfma_f32_16x16x32_bf16(oa[kk], bw, res[ot], 0, 0, 0);
    }
  }

  // write R back to own rows (disjoint per wave; own reads already done)
  #pragma unroll
  for (int ot = 0; ot < 4; ot++)
    #pragma unroll
    for (int r = 0; r < 4; r++)
      Sl[(w * 16 + q4 * 4 + r) * 68 + ot * 16 + il] = res[ot][r];
  __syncthreads();

  // final: out[o][t] = R[t][o] + x[o][t], coalesced over t
  const int tl = tid & 63, og = tid >> 6;
  float rv[16];
  #pragma unroll
  for (int jj = 0; jj < 4; jj++) {
    float4 t4 = *(const float4*)&Sl[tl * 68 + og * 16 + jj * 4];
    rv[jj*4+0] = t4.x; rv[jj*4+1] = t4.y; rv[jj*4+2] = t4.z; rv[jj*4+3] = t4.w;
  }
  #pragma unroll
  for (int j = 0; j < 16; j++) {
    const size_t idx = nbase + (size_t)(og * 16 + j) * TT + qt0 + tl;
    out[idx] = rv[j] + x[idx];
  }
}

// ---------------------------------------------------------------------------
extern "C" void kernel_launch(void* const* d_in, const int* in_sizes, int n_in,
                              void* d_out, int out_size, void* d_ws, size_t ws_size,
                              hipStream_t stream) {
  const float* x     = (const float*)d_in[0];
  const float* Wq    = (const float*)d_in[1];
  const float* Wk    = (const float*)d_in[2];
  const float* Wv    = (const float*)d_in[3];
  const float* Wo    = (const float*)d_in[4];
  const float* scale = (const float*)d_in[5];
  float* out = (float*)d_out;

  const size_t elems = (size_t)NB * CC * TT;
  bf16* qt = (bf16*)d_ws;
  bf16* kt = qt + elems;
  bf16* vv = kt + elems;

  dim3 grid(TT / 64, NB);   // (16, 128)
  dim3 block(256);

  qkv_proj<<<grid, block, 0, stream>>>(x, Wq, Wk, Wv, qt, kt, vv);
  attn_fused<<<grid, block, 0, stream>>>(qt, kt, vv, Wo, x, scale, out);
}

// Round 3
// 202.656 us; speedup vs baseline: 7.9061x; 1.4214x over previous
//
#include <hip/hip_runtime.h>
#include <hip/hip_bf16.h>

typedef __hip_bfloat16 bf16;
typedef __attribute__((ext_vector_type(8))) short short8;   // 8 bf16 = one MFMA A/B frag
typedef __attribute__((ext_vector_type(4))) float f32x4;    // one MFMA C/D frag

#define NB 128   // B*TO
#define CC 64    // channels
#define TT 1024  // time

__device__ __forceinline__ short f2bfs(float f) {
  bf16 h = __float2bfloat16(f);
  short s; __builtin_memcpy(&s, &h, 2); return s;
}

// ---------------------------------------------------------------------------
// Kernel 0: one-shot weight convert fp32->bf16 into ws.
// wb layout: [0:4096) Wq, [4096:8192) Wk, [8192:12288) Wv, [12288:16384) Wo.
// ---------------------------------------------------------------------------
__global__ __launch_bounds__(256) void wcvt(
    const float* __restrict__ Wq, const float* __restrict__ Wk,
    const float* __restrict__ Wv, const float* __restrict__ Wo,
    bf16* __restrict__ wb)
{
  const int i = blockIdx.x * 256 + threadIdx.x;   // 64 blocks -> 16384 threads
  float f;
  if      (i <  4096) f = Wq[i];
  else if (i <  8192) f = Wk[i - 4096];
  else if (i < 12288) f = Wv[i - 8192];
  else                f = Wo[i - 12288];
  wb[i] = __float2bfloat16(f);
}

// ---------------------------------------------------------------------------
// Kernel 1: MFMA q/k/v projections, one (n, 64-t tile) per block, 4 waves.
// xs[t][c] (transposed x, bf16) serves as A-operand for Q/K (D[t][o]) AND
// B-operand for V (D[o][t]); weight frags are contiguous 16B row reads.
// Outputs: qt/kt in [n][t][c], v in [n][c][t] — exactly what attn consumes.
// ---------------------------------------------------------------------------
__global__ __launch_bounds__(256) void qkv_mfma(
    const float* __restrict__ x, const bf16* __restrict__ wb,
    bf16* __restrict__ qt, bf16* __restrict__ kt, bf16* __restrict__ v)
{
  __shared__ short xs[64][70];   // stride 70: (3t + c/2)%32 -> <=2-way (free)

  const int n  = blockIdx.y;
  const int t0 = blockIdx.x * 64;
  const int tid = threadIdx.x;
  const int w  = tid >> 6, il = tid & 15, q4 = (tid & 63) >> 4;
  const size_t nbase = (size_t)n * CC * TT;

  // stage x^T tile (global: lanes vary t -> coalesced; LDS: conflict-free)
  for (int i = tid; i < 4096; i += 256) {
    int c = i >> 6, t = i & 63;
    xs[t][c] = f2bfs(x[nbase + (size_t)c * TT + t0 + t]);
  }
  __syncthreads();

  // x frag: rows w*16+il of xs, k contiguous. A-frag for Q/K, B-frag for V.
  short8 xa[2];
  #pragma unroll
  for (int kk = 0; kk < 2; kk++)
    xa[kk] = *(const short8*)&xs[w * 16 + il][kk * 32 + q4 * 8];

  const bf16* wq = wb;
  const bf16* wk = wb + 4096;
  const bf16* wv = wb + 8192;

  f32x4 aq[4], ak[4], av[4];
  #pragma unroll
  for (int i = 0; i < 4; i++) {
    aq[i] = (f32x4){0.f,0.f,0.f,0.f};
    ak[i] = (f32x4){0.f,0.f,0.f,0.f};
    av[i] = (f32x4){0.f,0.f,0.f,0.f};
  }

  #pragma unroll
  for (int kk = 0; kk < 2; kk++) {
    #pragma unroll
    for (int ot = 0; ot < 4; ot++) {
      const int ridx = (ot * 16 + il) * 64 + kk * 32 + q4 * 8;  // weight row frag
      short8 bq = *(const short8*)&wq[ridx];
      short8 bk = *(const short8*)&wk[ridx];
      short8 bv = *(const short8*)&wv[ridx];
      // Q,K: D[t][o] = xs^T-frag (A) x W^T-frag (B)
      aq[ot] = __builtin_amdgcn_mfma_f32_16x16x32_bf16(xa[kk], bq, aq[ot], 0, 0, 0);
      ak[ot] = __builtin_amdgcn_mfma_f32_16x16x32_bf16(xa[kk], bk, ak[ot], 0, 0, 0);
      // V: D[o][t] = Wv-frag (A) x x-frag (B)
      av[ot] = __builtin_amdgcn_mfma_f32_16x16x32_bf16(bv, xa[kk], av[ot], 0, 0, 0);
    }
  }

  // stores straight from C/D layout (row=q4*4+r, col=il)
  #pragma unroll
  for (int ot = 0; ot < 4; ot++) {
    #pragma unroll
    for (int r = 0; r < 4; r++) {
      const size_t qi = nbase + (size_t)(t0 + w * 16 + q4 * 4 + r) * 64 + ot * 16 + il;
      qt[qi] = __float2bfloat16(aq[ot][r]);
      kt[qi] = __float2bfloat16(ak[ot][r]);
      v[nbase + (size_t)(ot * 16 + q4 * 4 + r) * TT + t0 + w * 16 + il] =
          __float2bfloat16(av[ot][r]);
    }
  }
}

// ---------------------------------------------------------------------------
// Kernel 2: fused MFMA flash attention + output projection + residual.
// Block = (n, 64-query tile), 4 waves. mfma_f32_16x16x32_bf16 throughout.
// A-layout: A[m=lane&15][k=(lane>>4)*8+j]; B[k=(lane>>4)*8+j][n=lane&15];
// C/D: row=(lane>>4)*4+reg, col=lane&15  (m89/m120-verified layouts).
// ---------------------------------------------------------------------------
__global__ __launch_bounds__(256, 4) void attn_fused(
    const bf16* __restrict__ qt, const bf16* __restrict__ kt,
    const bf16* __restrict__ v,  const bf16* __restrict__ wob,
    const float* __restrict__ x, const float* __restrict__ scale_p,
    float* __restrict__ out)
{
  __shared__ short ks[64 * 72];    // K tile [s][c], bf16
  __shared__ short vs[64 * 72];    // V tile [c][s], bf16
  __shared__ float Sl[64 * 68];    // S fp32 [t][s]; P bf16 overlaid
  __shared__ float mrow[64], lrow[64], arow[64];
  __shared__ float pm[256], pl[256];

  short* Pl = (short*)Sl;

  const int n   = blockIdx.y;
  const int qt0 = blockIdx.x * 64;
  const int tid = threadIdx.x;
  const int w   = tid >> 6;
  const int il  = tid & 15;
  const int q4  = (tid & 63) >> 4;
  const size_t nbase = (size_t)n * CC * TT;
  const float scale = *scale_p;

  short8 qa[4][2];
  #pragma unroll
  for (int mt = 0; mt < 4; mt++)
    #pragma unroll
    for (int kk = 0; kk < 2; kk++)
      qa[mt][kk] = *(const short8*)&qt[nbase + (size_t)(qt0 + mt * 16 + il) * 64 + kk * 32 + q4 * 8];

  f32x4 oacc[4];
  #pragma unroll
  for (int ct = 0; ct < 4; ct++) oacc[ct] = (f32x4){0.f, 0.f, 0.f, 0.f};

  if (tid < 64) { mrow[tid] = -1e30f; lrow[tid] = 0.f; }

  const int row  = tid & 63;
  const int part = tid >> 6;

  #pragma unroll 1
  for (int st = 0; st < 16; st++) {
    const int s0 = st * 64;
    __syncthreads();

    #pragma unroll
    for (int p = 0; p < 2; p++) {
      int ci = tid + p * 256;
      int rr = ci >> 3, co = (ci & 7) * 8;
      *(short8*)&ks[rr * 72 + co] = *(const short8*)&kt[nbase + (size_t)(s0 + rr) * 64 + co];
      *(short8*)&vs[rr * 72 + co] = *(const short8*)&v[nbase + (size_t)rr * TT + s0 + co];
    }
    __syncthreads();

    // ---- QK^T: wave w owns s-cols [w*16, w*16+16)
    short8 bk0 = *(const short8*)&ks[(w * 16 + il) * 72 + q4 * 8];
    short8 bk1 = *(const short8*)&ks[(w * 16 + il) * 72 + 32 + q4 * 8];
    #pragma unroll
    for (int mt = 0; mt < 4; mt++) {
      f32x4 sa = (f32x4){0.f, 0.f, 0.f, 0.f};
      sa = __builtin_amdgcn_mfma_f32_16x16x32_bf16(qa[mt][0], bk0, sa, 0, 0, 0);
      sa = __builtin_amdgcn_mfma_f32_16x16x32_bf16(qa[mt][1], bk1, sa, 0, 0, 0);
      #pragma unroll
      for (int r = 0; r < 4; r++)
        Sl[(mt * 16 + q4 * 4 + r) * 68 + w * 16 + il] = sa[r] * scale;
    }
    __syncthreads();

    // ---- softmax (thread = (row, 16-wide part))
    float sv[16];
    #pragma unroll
    for (int jj = 0; jj < 4; jj++) {
      float4 t4 = *(const float4*)&Sl[row * 68 + part * 16 + jj * 4];
      sv[jj*4+0] = t4.x; sv[jj*4+1] = t4.y; sv[jj*4+2] = t4.z; sv[jj*4+3] = t4.w;
    }
    float pmax = sv[0];
    #pragma unroll
    for (int i = 1; i < 16; i++) pmax = fmaxf(pmax, sv[i]);
    pm[part * 64 + row] = pmax;
    const float mold = mrow[row];
    __syncthreads();
    float mnew = fmaxf(fmaxf(pm[row], pm[64 + row]), fmaxf(pm[128 + row], pm[192 + row]));
    mnew = fmaxf(mold, mnew);
    const float alpha = __expf(mold - mnew);
    float psum = 0.f;
    short pu[16];
    #pragma unroll
    for (int i = 0; i < 16; i++) {
      float p = __expf(sv[i] - mnew);
      psum += p;
      pu[i] = f2bfs(p);
    }
    *(short8*)&Pl[row * 72 + part * 16]     = *(const short8*)&pu[0];
    *(short8*)&Pl[row * 72 + part * 16 + 8] = *(const short8*)&pu[8];
    pl[part * 64 + row] = psum;
    if (part == 0) { mrow[row] = mnew; arow[row] = alpha; }
    __syncthreads();
    if (part == 0)
      lrow[row] = lrow[row] * alpha + pl[row] + pl[64 + row] + pl[128 + row] + pl[192 + row];

    // ---- PV: wave w owns t-rows [w*16, w*16+16)
    float ar[4];
    #pragma unroll
    for (int r = 0; r < 4; r++) ar[r] = arow[w * 16 + q4 * 4 + r];
    #pragma unroll
    for (int ct = 0; ct < 4; ct++)
      #pragma unroll
      for (int r = 0; r < 4; r++) oacc[ct][r] *= ar[r];

    short8 pa0 = *(const short8*)&Pl[(w * 16 + il) * 72 + q4 * 8];
    short8 pa1 = *(const short8*)&Pl[(w * 16 + il) * 72 + 32 + q4 * 8];
    #pragma unroll
    for (int ct = 0; ct < 4; ct++) {
      short8 bv0 = *(const short8*)&vs[(ct * 16 + il) * 72 + q4 * 8];
      short8 bv1 = *(const short8*)&vs[(ct * 16 + il) * 72 + 32 + q4 * 8];
      oacc[ct] = __builtin_amdgcn_mfma_f32_16x16x32_bf16(pa0, bv0, oacc[ct], 0, 0, 0);
      oacc[ct] = __builtin_amdgcn_mfma_f32_16x16x32_bf16(pa1, bv1, oacc[ct], 0, 0, 0);
    }
  }

  // ================= epilogue: normalize, Wo projection, +x, store ==========
  __syncthreads();

  float li[4];
  #pragma unroll
  for (int r = 0; r < 4; r++) li[r] = 1.f / lrow[w * 16 + q4 * 4 + r];
  #pragma unroll
  for (int ct = 0; ct < 4; ct++) {
    #pragma unroll
    for (int r = 0; r < 4; r++)
      Sl[(w * 16 + q4 * 4 + r) * 68 + ct * 16 + il] = oacc[ct][r] * li[r];
  }
  __syncthreads();

  short8 oa[2];
  #pragma unroll
  for (int kk = 0; kk < 2; kk++) {
    float4 f0 = *(const float4*)&Sl[(w * 16 + il) * 68 + kk * 32 + q4 * 8];
    float4 f1 = *(const float4*)&Sl[(w * 16 + il) * 68 + kk * 32 + q4 * 8 + 4];
    short tmp[8] = { f2bfs(f0.x), f2bfs(f0.y), f2bfs(f0.z), f2bfs(f0.w),
                     f2bfs(f1.x), f2bfs(f1.y), f2bfs(f1.z), f2bfs(f1.w) };
    oa[kk] = *(const short8*)&tmp[0];
  }

  f32x4 res[4];
  #pragma unroll
  for (int ot = 0; ot < 4; ot++) res[ot] = (f32x4){0.f, 0.f, 0.f, 0.f};
  #pragma unroll
  for (int ot = 0; ot < 4; ot++) {
    #pragma unroll
    for (int kk = 0; kk < 2; kk++) {
      short8 bw = *(const short8*)&wob[(size_t)(ot * 16 + il) * 64 + kk * 32 + q4 * 8];
      res[ot] = __builtin_amdgcn_mfma_f32_16x16x32_bf16(oa[kk], bw, res[ot], 0, 0, 0);
    }
  }

  #pragma unroll
  for (int ot = 0; ot < 4; ot++)
    #pragma unroll
    for (int r = 0; r < 4; r++)
      Sl[(w * 16 + q4 * 4 + r) * 68 + ot * 16 + il] = res[ot][r];
  __syncthreads();

  const int tl = tid & 63, og = tid >> 6;
  float rv[16];
  #pragma unroll
  for (int jj = 0; jj < 4; jj++) {
    float4 t4 = *(const float4*)&Sl[tl * 68 + og * 16 + jj * 4];
    rv[jj*4+0] = t4.x; rv[jj*4+1] = t4.y; rv[jj*4+2] = t4.z; rv[jj*4+3] = t4.w;
  }
  #pragma unroll
  for (int j = 0; j < 16; j++) {
    const size_t idx = nbase + (size_t)(og * 16 + j) * TT + qt0 + tl;
    out[idx] = rv[j] + x[idx];
  }
}

// ---------------------------------------------------------------------------
extern "C" void kernel_launch(void* const* d_in, const int* in_sizes, int n_in,
                              void* d_out, int out_size, void* d_ws, size_t ws_size,
                              hipStream_t stream) {
  const float* x     = (const float*)d_in[0];
  const float* Wq    = (const float*)d_in[1];
  const float* Wk    = (const float*)d_in[2];
  const float* Wv    = (const float*)d_in[3];
  const float* Wo    = (const float*)d_in[4];
  const float* scale = (const float*)d_in[5];
  float* out = (float*)d_out;

  // ws layout: wb (16384 bf16 = 32 KB), then qt/kt/v (16.78 MB each)
  const size_t elems = (size_t)NB * CC * TT;
  bf16* wb = (bf16*)d_ws;
  bf16* qtb = wb + 16384;
  bf16* ktb = qtb + elems;
  bf16* vv  = ktb + elems;

  dim3 grid(TT / 64, NB);   // (16, 128)
  dim3 block(256);

  wcvt<<<64, 256, 0, stream>>>(Wq, Wk, Wv, Wo, wb);
  qkv_mfma<<<grid, block, 0, stream>>>(x, wb, qtb, ktb, vv);
  attn_fused<<<grid, block, 0, stream>>>(qtb, ktb, vv, wb + 12288, x, scale, out);
}